// Round 13
// baseline (128.033 us; speedup 1.0000x reference)
//
#include <hip/hip_runtime.h>
#include <hip/hip_bf16.h>
#include <stdint.h>

typedef unsigned short u16;
typedef __attribute__((ext_vector_type(8))) short bf16x8;
typedef __attribute__((ext_vector_type(4))) float f32x4;
typedef __attribute__((ext_vector_type(16))) float f32x16;

#define HW 4096
#define CC 256
// 0.125 (1/sqrt(64)) * log2(e): folded into Q so softmax can use exp2 directly
#define QSCALE 0.18033688011112042f

__device__ __forceinline__ u16 f2bf(float f) {
    union { float f; uint32_t i; } v; v.f = f;
    uint32_t x = v.i;
    return (u16)((x + 0x7fffu + ((x >> 16) & 1u)) >> 16);
}

__device__ __forceinline__ float fast_exp2(float x) {
#if __has_builtin(__builtin_amdgcn_exp2f)
    return __builtin_amdgcn_exp2f(x);
#else
    return exp2f(x);
#endif
}

__device__ __forceinline__ unsigned cvt_pk_bf16(float lo, float hi) {
    unsigned r;
    asm("v_cvt_pk_bf16_f32 %0, %1, %2" : "=v"(r) : "v"(lo), "v"(hi));
    return r;
}

// a' = [a_low | b_low], b' = [a_high | b_high]  (lane ranges [0:31] | [32:63])
__device__ __forceinline__ void plane_swap(unsigned& a, unsigned& b) {
#if __has_builtin(__builtin_amdgcn_permlane32_swap)
    auto r = __builtin_amdgcn_permlane32_swap(a, b, false, false);
    a = r[0]; b = r[1];
#else
    unsigned ax = __shfl_xor((int)a, 32);
    unsigned bx = __shfl_xor((int)b, 32);
    bool hi = (threadIdx.x & 32) != 0;
    unsigned na = hi ? bx : a;
    unsigned nb = hi ? b : ax;
    a = na; b = nb;
#endif
}

#define MFMA16(a, b, c) __builtin_amdgcn_mfma_f32_16x16x32_bf16(a, b, c, 0, 0, 0)
#define MFMA32(a, b, c) __builtin_amdgcn_mfma_f32_32x32x16_bf16(a, b, c, 0, 0, 0)

// ---------------- K0+K1 fused: GroupNorm partial stats (1024 blks) + weight convert --
__global__ void k_wsc(const float* __restrict__ qkv_w, const float* __restrict__ proj_w,
                      const float* __restrict__ x,
                      u16* __restrict__ wqkv, u16* __restrict__ wproj, float* __restrict__ stats) {
    int bid = blockIdx.x;
    if (bid < 1024) {
        // partial sums per (b,g,slab): slab = 4096 contiguous floats of the group slab
        int bg = bid >> 3, slab = bid & 7;
        const float4* p = reinterpret_cast<const float4*>(x + (size_t)bg * 32768 + slab * 4096);
        float s = 0.f, ss = 0.f;
        for (int i = 0; i < 4; ++i) {
            float4 v = p[threadIdx.x + i * 256];
            s += v.x + v.y + v.z + v.w;
            ss += v.x * v.x + v.y * v.y + v.z * v.z + v.w * v.w;
        }
        __shared__ float rs[256], rss[256];
        rs[threadIdx.x] = s; rss[threadIdx.x] = ss;
        __syncthreads();
        for (int off = 128; off > 0; off >>= 1) {
            if (threadIdx.x < off) { rs[threadIdx.x] += rs[threadIdx.x + off]; rss[threadIdx.x] += rss[threadIdx.x + off]; }
            __syncthreads();
        }
        if (threadIdx.x == 0) {
            stats[bid * 2] = rs[0];
            stats[bid * 2 + 1] = rss[0];
        }
    } else {
        int i = (bid - 1024) * 256 + threadIdx.x;
        if (i < 768 * 256) {
            int o = i >> 8;
            float sc = (o < 256) ? QSCALE : 1.0f;
            wqkv[i] = f2bf(qkv_w[i] * sc);
        }
        int j = i - 768 * 256;
        if (j >= 0 && j < 256 * 256) wproj[j] = f2bf(proj_w[j]);
    }
}

// ---------------- K3': fused GroupNorm + QKV GEMM -----------------------------------
// Per block: (1) transpose stage: x[b][c][n0..n0+128) fp32 -> normalize -> bf16 ->
// hB[128 n][264] LDS (c-pairs packed as u32; pitch 264 u16 = 132 dw = 4 mod 32 ->
// conflict-free writes). (2) GEMM k-loop reads B-fragments straight from hB (no
// per-kt B staging); only A (wqkv) staged per kt. Eliminates k_gnt + h_t entirely.
__global__ __launch_bounds__(256) void k_qkvf(const u16* __restrict__ wqkv, const float* __restrict__ x,
                                              const float* __restrict__ stats,
                                              const float* __restrict__ gamma, const float* __restrict__ beta,
                                              const float* __restrict__ qkv_b,
                                              u16* __restrict__ qk_t, u16* __restrict__ v_o) {
    int bid = blockIdx.x;          // 4 * 6 * 32 = 768
    int b = bid / 192;
    int rem = bid % 192;
    int om = rem >> 5;             // 0..5
    int nb = rem & 31;
    int o0 = om * 128, n0 = nb * 128;
    int t = threadIdx.x;
    int wid = t >> 6, lane = t & 63;
    int wm = wid >> 1, wn = wid & 1;
    int l15 = lane & 15, lg = lane >> 4;

    __shared__ u16 sA[128 * 40];       // 10240 B
    __shared__ u16 hB[128 * 264];      // 67584 B  [n][c] normalized bf16, pitch 264

    // ---- transpose + normalize stage ----
    {
        int cpair = t >> 1;            // 0..127
        int nh = t & 1;                // 64-n half
        int c0 = cpair * 2;
        float mu[2], rsg[2], ga[2], be[2];
#pragma unroll
        for (int e = 0; e < 2; ++e) {
            int c = c0 + e;
            int g = c >> 3;
            float sum = 0.f, ssum = 0.f;
            for (int s = 0; s < 8; ++s) {
                sum  += stats[((b * 32 + g) * 8 + s) * 2];
                ssum += stats[((b * 32 + g) * 8 + s) * 2 + 1];
            }
            float m = sum * (1.f / 32768.f);
            float var = ssum * (1.f / 32768.f) - m * m;
            mu[e] = m;
            rsg[e] = rsqrtf(var + 1e-5f);
            ga[e] = gamma[c];
            be[e] = beta[c];
        }
        const float4* px0 = reinterpret_cast<const float4*>(x + ((size_t)(b * CC + c0)) * HW + n0 + nh * 64);
        const float4* px1 = reinterpret_cast<const float4*>(x + ((size_t)(b * CC + c0 + 1)) * HW + n0 + nh * 64);
#pragma unroll
        for (int j4 = 0; j4 < 16; ++j4) {
            float4 v0 = px0[j4];
            float4 v1 = px1[j4];
            float a0[4] = {v0.x, v0.y, v0.z, v0.w};
            float a1[4] = {v1.x, v1.y, v1.z, v1.w};
#pragma unroll
            for (int k = 0; k < 4; ++k) {
                u16 lo = f2bf((a0[k] - mu[0]) * rsg[0] * ga[0] + be[0]);
                u16 hi = f2bf((a1[k] - mu[1]) * rsg[1] * ga[1] + be[1]);
                unsigned pk = (unsigned)lo | ((unsigned)hi << 16);
                *reinterpret_cast<unsigned*>(&hB[(nh * 64 + j4 * 4 + k) * 264 + c0]) = pk;
            }
        }
    }
    __syncthreads();

    // ---- GEMM k-loop: stage A only; B fragments read from hB ----
    f32x4 acc[4][4];
    for (int i = 0; i < 4; ++i) for (int j = 0; j < 4; ++j) acc[i][j] = (f32x4)0.f;

    const u16* gA = wqkv + (size_t)o0 * 256;
    int row = t >> 1, half = t & 1;

    for (int kt = 0; kt < 8; ++kt) {
        __syncthreads();
        {
            const uint4* pa = reinterpret_cast<const uint4*>(gA + (size_t)row * 256 + kt * 32 + half * 16);
            uint4 a0 = pa[0], a1 = pa[1];
            *reinterpret_cast<uint4*>(&sA[row * 40 + half * 16]) = a0;
            *reinterpret_cast<uint4*>(&sA[row * 40 + half * 16 + 8]) = a1;
        }
        __syncthreads();
        bf16x8 af[4], bfr[4];
        for (int mt = 0; mt < 4; ++mt)
            af[mt] = *reinterpret_cast<const bf16x8*>(&sA[(wm * 64 + mt * 16 + l15) * 40 + lg * 8]);
        for (int nt = 0; nt < 4; ++nt)
            bfr[nt] = *reinterpret_cast<const bf16x8*>(&hB[(wn * 64 + nt * 16 + l15) * 264 + kt * 32 + lg * 8]);
        for (int mt = 0; mt < 4; ++mt)
            for (int nt = 0; nt < 4; ++nt)
                acc[mt][nt] = MFMA16(af[mt], bfr[nt], acc[mt][nt]);
    }

    // epilogue
    if (o0 < 512) {
        for (int mt = 0; mt < 4; ++mt) {
            int ob = o0 + wm * 64 + mt * 16 + lg * 4;
            float bias[4];
            for (int r = 0; r < 4; ++r) {
                int o = ob + r;
                bias[r] = qkv_b[o] * (o < 256 ? QSCALE : 1.0f);
            }
            for (int nt = 0; nt < 4; ++nt) {
                int n = n0 + wn * 64 + nt * 16 + l15;
                union { u16 u[4]; uint2 q; } pk;
                for (int r = 0; r < 4; ++r) pk.u[r] = f2bf(acc[mt][nt][r] + bias[r]);
                *reinterpret_cast<uint2*>(qk_t + ((size_t)b * HW + n) * 512 + ob) = pk.q;
            }
        }
    } else {
        for (int mt = 0; mt < 4; ++mt) {
            int ob = o0 + wm * 64 + mt * 16 + lg * 4;
            for (int nt = 0; nt < 4; ++nt) {
                int n = n0 + wn * 64 + nt * 16 + l15;
                for (int r = 0; r < 4; ++r) {
                    int o = ob + r;
                    float bias = qkv_b[o];
                    v_o[((size_t)b * 256 + (o - 512)) * HW + n] = f2bf(acc[mt][nt][r] + bias);
                }
            }
        }
    }
}

// ---------------- K4: flash attention, swapped 32x32, 8-wave key-split --------------
// r9 structure verbatim (best measured: 77.4 us). Grid 512 XCD-swizzled; K+V
// double-buffered LDS; prefetch issued AFTER the barrier (not drained by hipcc's
// pre-barrier vmcnt(0)); T5 setprio around MFMA clusters; fixed softmax max
// (m=0; logits ~N(0,0.1), fp32 sum safe to ~2^110) -> kg partials exactly
// additive: O = (O0+O1)/(l0+l1), combined via LDS at end.
// NOTE (r11/r12 lesson): register budget is EXACTLY saturated (64 VGPR + 64 AGPR
// accumulators at 4 waves/SIMD); do NOT extend liveness here.
__global__ __launch_bounds__(512, 4) void k_attn(const u16* __restrict__ qk_t, const u16* __restrict__ v_o,
                                                 u16* __restrict__ ao_t) {
    int bid = blockIdx.x;
    int swz = (bid & 7) * 64 + (bid >> 3);   // bijective; 64 consecutive tiles per XCD
    int qb = swz & 31, head = (swz >> 5) & 3, b = swz >> 7;
    int n0 = qb * 128;
    int t = threadIdx.x;
    int kg = t >> 8;                   // key group 0/1
    int wq = (t >> 6) & 3;             // q strip within group
    int lane = t & 63, l31 = lane & 31, h = lane >> 5;

    __shared__ u16 lds[2 * 2 * 2 * 64 * 72];   // 73728 B: [group][buf][K/V][64][72]

    // hoist Q fragments (B-operand layout: lane n=l31, c = h*8+j) — direct global
    const u16* qbase = qk_t + ((size_t)b * HW + n0 + wq * 32 + l31) * 512 + head * 64 + h * 8;
    bf16x8 qf[4];
#pragma unroll
    for (int cs = 0; cs < 4; ++cs) qf[cs] = *reinterpret_cast<const bf16x8*>(qbase + cs * 16);

    const u16* gK = qk_t + (size_t)b * HW * 512 + 256 + head * 64;
    const u16* gV = v_o + ((size_t)b * 256 + head * 64) * (size_t)HW;

    int tIn = t & 255;
    int srow = tIn >> 3, sch = tIn & 7;  // staging within group: 2 rows/thread/operand
    const u16* pk0 = gK + (size_t)(kg * 2048 + srow) * 512 + sch * 8;
    const u16* pk1 = pk0 + 32 * 512;
    const u16* pv0 = gV + (size_t)srow * HW + kg * 2048 + sch * 8;
    const u16* pv1 = pv0 + 32 * HW;
    uint4 rk0 = *reinterpret_cast<const uint4*>(pk0);
    uint4 rk1 = *reinterpret_cast<const uint4*>(pk1);
    uint4 rv0 = *reinterpret_cast<const uint4*>(pv0);
    uint4 rv1 = *reinterpret_cast<const uint4*>(pv1);

    f32x16 o0 = (f32x16)0.f, o1 = (f32x16)0.f;
    float l_run = 0.f;
    u16* gb = lds + kg * 18432;

    for (int ti = 0; ti < 32; ++ti) {
        u16* bK = gb + (ti & 1) * 9216;
        u16* bV = bK + 4608;
        *reinterpret_cast<uint4*>(bK + srow * 72 + sch * 8) = rk0;
        *reinterpret_cast<uint4*>(bK + (srow + 32) * 72 + sch * 8) = rk1;
        *reinterpret_cast<uint4*>(bV + srow * 72 + sch * 8) = rv0;
        *reinterpret_cast<uint4*>(bV + (srow + 32) * 72 + sch * 8) = rv1;
        __syncthreads();   // vmcnt already 0 here (writes consumed the loads)

        if (ti < 31) {     // prefetch issued AFTER the barrier: not drained, flies
            pk0 += 64 * 512; pk1 += 64 * 512; pv0 += 64; pv1 += 64;
            rk0 = *reinterpret_cast<const uint4*>(pk0);
            rk1 = *reinterpret_cast<const uint4*>(pk1);
            rv0 = *reinterpret_cast<const uint4*>(pv0);
            rv1 = *reinterpret_cast<const uint4*>(pv1);
        }

        // S^T[k][q] = K[k][c] * Q^T[c][q]
        f32x16 s0 = (f32x16)0.f, s1 = (f32x16)0.f;
        __builtin_amdgcn_s_setprio(1);
#pragma unroll
        for (int cs = 0; cs < 4; ++cs) {
            bf16x8 k0 = *reinterpret_cast<const bf16x8*>(bK + l31 * 72 + cs * 16 + h * 8);
            bf16x8 k1 = *reinterpret_cast<const bf16x8*>(bK + (l31 + 32) * 72 + cs * 16 + h * 8);
            s0 = MFMA32(k0, qf[cs], s0);
            s1 = MFMA32(k1, qf[cs], s1);
        }
        __builtin_amdgcn_s_setprio(0);

        // fixed-max softmax: P = exp2(S) directly; in-lane partial sum
        float ps = 0.f;
#pragma unroll
        for (int i = 0; i < 16; ++i) { float e = fast_exp2(s0[i]); s0[i] = e; ps += e; }
#pragma unroll
        for (int i = 0; i < 16; ++i) { float e = fast_exp2(s1[i]); s1[i] = e; ps += e; }
        l_run += ps;

        // pack P to bf16 dwords: dws[kt][2a+p] covers k = kt*32 + 8a + 4h + 2p + {0,1}
        unsigned dws[2][8];
#pragma unroll
        for (int a = 0; a < 4; ++a) {
            dws[0][2 * a]     = cvt_pk_bf16(s0[4 * a],     s0[4 * a + 1]);
            dws[0][2 * a + 1] = cvt_pk_bf16(s0[4 * a + 2], s0[4 * a + 3]);
            dws[1][2 * a]     = cvt_pk_bf16(s1[4 * a],     s1[4 * a + 1]);
            dws[1][2 * a + 1] = cvt_pk_bf16(s1[4 * a + 2], s1[4 * a + 3]);
        }
        // build PV B-fragments: frag[ks] needs k = 16ks + 8h + {0..7}
        bf16x8 pf[4];
#pragma unroll
        for (int ks = 0; ks < 4; ++ks) {
            int kt = ks >> 1, sf = ks & 1;
            unsigned A0 = dws[kt][4 * sf + 0], B0 = dws[kt][4 * sf + 2];
            unsigned A1 = dws[kt][4 * sf + 1], B1 = dws[kt][4 * sf + 3];
            plane_swap(A0, B0);
            plane_swap(A1, B1);
            union { unsigned d[4]; bf16x8 v; } u;
            u.d[0] = A0; u.d[1] = A1; u.d[2] = B0; u.d[3] = B1;
            pf[ks] = u.v;
        }

        // O^T[d][q] += V^T[d][k] * P^T[k][q]
        __builtin_amdgcn_s_setprio(1);
#pragma unroll
        for (int ks = 0; ks < 4; ++ks) {
            bf16x8 v0 = *reinterpret_cast<const bf16x8*>(bV + l31 * 72 + ks * 16 + h * 8);
            bf16x8 v1 = *reinterpret_cast<const bf16x8*>(bV + (l31 + 32) * 72 + ks * 16 + h * 8);
            o0 = MFMA32(v0, pf[ks], o0);
            o1 = MFMA32(v1, pf[ks], o1);
        }
        __builtin_amdgcn_s_setprio(0);
    }

    // full row-sum: add the other 32-key half within this group's tile columns
    l_run += __shfl_xor(l_run, 32);

    // -------- combine group partials (exactly additive under fixed max) --------
    float* Of = (float*)lds;                 // [wq][32 regs][64 lanes] = 32 KB
    float* Lf = (float*)lds + 8192;          // [wq*64+lane] = 1 KB
    u16* E = lds + 18432;                    // [128 q][72] u16 funnel (group-1 region)

    __syncthreads();                         // all compute done; LDS reusable
    if (kg == 1) {
#pragma unroll
        for (int i = 0; i < 16; ++i) {
            Of[wq * 2048 + i * 64 + lane] = o0[i];
            Of[wq * 2048 + (16 + i) * 64 + lane] = o1[i];
        }
        Lf[wq * 64 + lane] = l_run;
    }
    __syncthreads();
    if (kg == 0) {
#pragma unroll
        for (int i = 0; i < 16; ++i) {
            o0[i] += Of[wq * 2048 + i * 64 + lane];
            o1[i] += Of[wq * 2048 + (16 + i) * 64 + lane];
        }
        l_run += Lf[wq * 64 + lane];
        float inv = 1.0f / l_run;
        int qrow = wq * 32 + l31;
#pragma unroll
        for (int r = 0; r < 16; ++r) {
            int d = (r & 3) + 8 * (r >> 2) + 4 * h;
            E[qrow * 72 + d]      = f2bf(o0[r] * inv);
            E[qrow * 72 + 32 + d] = f2bf(o1[r] * inv);
        }
    }
    __syncthreads();
#pragma unroll
    for (int i = 0; i < 2; ++i) {
        int item = i * 512 + t;
        int row = item >> 3, cb = item & 7;
        uint4 w = *reinterpret_cast<const uint4*>(E + row * 72 + cb * 8);
        *reinterpret_cast<uint4*>(ao_t + ((size_t)b * HW + n0 + row) * 256 + head * 64 + cb * 8) = w;
    }
}

// ---------------- K5: proj GEMM + bias + residual -> out fp32 -----------------------
// BN=64 tiles -> grid 512 = 2 blocks/CU for latency hiding on the 136 MB epilogue.
__global__ __launch_bounds__(256) void k_proj(const u16* __restrict__ wproj, const u16* __restrict__ ao_t,
                                              const float* __restrict__ proj_b, const float* __restrict__ x,
                                              float* __restrict__ out) {
    int bid = blockIdx.x;          // 4 * 2 * 64 = 512
    int b = bid >> 7;
    int om = (bid >> 6) & 1;
    int nb = bid & 63;
    int o0 = om * 128, n0 = nb * 64;
    int t = threadIdx.x;
    int wid = t >> 6, lane = t & 63;
    int wm = wid >> 1, wn = wid & 1;
    int l15 = lane & 15, lg = lane >> 4;

    __shared__ u16 sA[128 * 40], sB[64 * 40];
    f32x4 acc[4][2];
    for (int i = 0; i < 4; ++i) for (int j = 0; j < 2; ++j) acc[i][j] = (f32x4)0.f;

    const u16* gA = wproj + (size_t)o0 * 256;
    const u16* gB = ao_t + ((size_t)b * HW + n0) * CC;
    int rowA = t >> 1, halfA = t & 1;
    int rowB = t >> 2, qB = t & 3;

    for (int kt = 0; kt < 8; ++kt) {
        __syncthreads();
        {
            const uint4* pa = reinterpret_cast<const uint4*>(gA + (size_t)rowA * 256 + kt * 32 + halfA * 16);
            uint4 a0 = pa[0], a1 = pa[1];
            uint4 b0 = *reinterpret_cast<const uint4*>(gB + (size_t)rowB * 256 + kt * 32 + qB * 8);
            *reinterpret_cast<uint4*>(&sA[rowA * 40 + halfA * 16]) = a0;
            *reinterpret_cast<uint4*>(&sA[rowA * 40 + halfA * 16 + 8]) = a1;
            *reinterpret_cast<uint4*>(&sB[rowB * 40 + qB * 8]) = b0;
        }
        __syncthreads();
        bf16x8 af[4], bfr[2];
        for (int mt = 0; mt < 4; ++mt)
            af[mt] = *reinterpret_cast<const bf16x8*>(&sA[(wm * 64 + mt * 16 + l15) * 40 + lg * 8]);
        for (int nt = 0; nt < 2; ++nt)
            bfr[nt] = *reinterpret_cast<const bf16x8*>(&sB[(wn * 32 + nt * 16 + l15) * 40 + lg * 8]);
        for (int mt = 0; mt < 4; ++mt)
            for (int nt = 0; nt < 2; ++nt)
                acc[mt][nt] = MFMA16(af[mt], bfr[nt], acc[mt][nt]);
    }

    for (int mt = 0; mt < 4; ++mt) {
        int ob = o0 + wm * 64 + mt * 16 + lg * 4;
        for (int nt = 0; nt < 2; ++nt) {
            int n = n0 + wn * 32 + nt * 16 + l15;
            for (int r = 0; r < 4; ++r) {
                int o = ob + r;
                size_t idx = ((size_t)(b * CC + o)) * HW + n;
                out[idx] = acc[mt][nt][r] + proj_b[o] + x[idx];
            }
        }
    }
}

// ---------------- launcher ----------------------------------------------------------
extern "C" void kernel_launch(void* const* d_in, const int* in_sizes, int n_in,
                              void* d_out, int out_size, void* d_ws, size_t ws_size,
                              hipStream_t stream) {
    const float* x      = (const float*)d_in[0];
    const float* gamma  = (const float*)d_in[1];
    const float* beta   = (const float*)d_in[2];
    const float* qkv_w  = (const float*)d_in[3];
    const float* qkv_b  = (const float*)d_in[4];
    const float* proj_w = (const float*)d_in[5];
    const float* proj_b = (const float*)d_in[6];
    float* out = (float*)d_out;
    char* ws = (char*)d_ws;

    float* stats = (float*)ws;                                   // 8 KB (1024 partials x2)
    u16* wqkv  = (u16*)(ws + 8192);                              // 384 KB
    u16* wproj = (u16*)(ws + 8192 + 393216);                     // 128 KB
    u16* qk_t  = (u16*)(ws + 1048576);                           // 16 MB [b][n][512]
    u16* v_o   = (u16*)(ws + 1048576 + 16777216);                // 8 MB  [b][256][n]
    u16* ao_t  = (u16*)(ws + 1048576 + 16777216 + 8388608);      // 8 MB  [b][n][c]

    k_wsc<<<dim3(2048), dim3(256), 0, stream>>>(qkv_w, proj_w, x, wqkv, wproj, stats);
    k_qkvf<<<dim3(768), dim3(256), 0, stream>>>(wqkv, x, stats, gamma, beta, qkv_b, qk_t, v_o);
    k_attn<<<dim3(512), dim3(512), 0, stream>>>(qk_t, v_o, ao_t);
    k_proj<<<dim3(512), dim3(256), 0, stream>>>(wproj, ao_t, proj_b, x, out);
}

// Round 14
// 122.817 us; speedup vs baseline: 1.0425x; 1.0425x over previous
//
#include <hip/hip_runtime.h>
#include <hip/hip_bf16.h>
#include <stdint.h>

typedef unsigned short u16;
typedef __attribute__((ext_vector_type(8))) short bf16x8;
typedef __attribute__((ext_vector_type(4))) float f32x4;
typedef __attribute__((ext_vector_type(16))) float f32x16;

#define HW 4096
#define CC 256
// 0.125 (1/sqrt(64)) * log2(e): folded into Q so softmax can use exp2 directly
#define QSCALE 0.18033688011112042f

__device__ __forceinline__ u16 f2bf(float f) {
    union { float f; uint32_t i; } v; v.f = f;
    uint32_t x = v.i;
    return (u16)((x + 0x7fffu + ((x >> 16) & 1u)) >> 16);
}

__device__ __forceinline__ float fast_exp2(float x) {
#if __has_builtin(__builtin_amdgcn_exp2f)
    return __builtin_amdgcn_exp2f(x);
#else
    return exp2f(x);
#endif
}

__device__ __forceinline__ unsigned cvt_pk_bf16(float lo, float hi) {
    unsigned r;
    asm("v_cvt_pk_bf16_f32 %0, %1, %2" : "=v"(r) : "v"(lo), "v"(hi));
    return r;
}

// a' = [a_low | b_low], b' = [a_high | b_high]  (lane ranges [0:31] | [32:63])
__device__ __forceinline__ void plane_swap(unsigned& a, unsigned& b) {
#if __has_builtin(__builtin_amdgcn_permlane32_swap)
    auto r = __builtin_amdgcn_permlane32_swap(a, b, false, false);
    a = r[0]; b = r[1];
#else
    unsigned ax = __shfl_xor((int)a, 32);
    unsigned bx = __shfl_xor((int)b, 32);
    bool hi = (threadIdx.x & 32) != 0;
    unsigned na = hi ? bx : a;
    unsigned nb = hi ? b : ax;
    a = na; b = nb;
#endif
}

#define MFMA16(a, b, c) __builtin_amdgcn_mfma_f32_16x16x32_bf16(a, b, c, 0, 0, 0)
#define MFMA32(a, b, c) __builtin_amdgcn_mfma_f32_32x32x16_bf16(a, b, c, 0, 0, 0)

// ---------------- K0+K1 fused: GroupNorm partial stats (1024 blks) + weight convert --
__global__ void k_wsc(const float* __restrict__ qkv_w, const float* __restrict__ proj_w,
                      const float* __restrict__ x,
                      u16* __restrict__ wqkv, u16* __restrict__ wproj, float* __restrict__ stats) {
    int bid = blockIdx.x;
    if (bid < 1024) {
        // partial sums per (b,g,slab): slab = 4096 contiguous floats of the group slab
        int bg = bid >> 3, slab = bid & 7;
        const float4* p = reinterpret_cast<const float4*>(x + (size_t)bg * 32768 + slab * 4096);
        float s = 0.f, ss = 0.f;
        for (int i = 0; i < 4; ++i) {
            float4 v = p[threadIdx.x + i * 256];
            s += v.x + v.y + v.z + v.w;
            ss += v.x * v.x + v.y * v.y + v.z * v.z + v.w * v.w;
        }
        __shared__ float rs[256], rss[256];
        rs[threadIdx.x] = s; rss[threadIdx.x] = ss;
        __syncthreads();
        for (int off = 128; off > 0; off >>= 1) {
            if (threadIdx.x < off) { rs[threadIdx.x] += rs[threadIdx.x + off]; rss[threadIdx.x] += rss[threadIdx.x + off]; }
            __syncthreads();
        }
        if (threadIdx.x == 0) {
            stats[bid * 2] = rs[0];
            stats[bid * 2 + 1] = rss[0];
        }
    } else {
        int i = (bid - 1024) * 256 + threadIdx.x;
        if (i < 768 * 256) {
            int o = i >> 8;
            float sc = (o < 256) ? QSCALE : 1.0f;
            wqkv[i] = f2bf(qkv_w[i] * sc);
        }
        int j = i - 768 * 256;
        if (j >= 0 && j < 256 * 256) wproj[j] = f2bf(proj_w[j]);
    }
}

// ---------------- K2: GroupNorm apply (reduce partials inline) + transpose ----------
__global__ __launch_bounds__(256) void k_gnt(const float* __restrict__ x, const float* __restrict__ stats,
                                             const float* __restrict__ gamma, const float* __restrict__ beta,
                                             u16* __restrict__ h_t) {
    int bid = blockIdx.x;          // 4 * 4 * 64 = 1024
    int b = bid >> 8;
    int cb = (bid >> 6) & 3;
    int nb = bid & 63;
    int t = threadIdx.x;
    int cl = t >> 2;               // 0..63
    int ch = t & 3;                // 16-wide n (then c) chunk
    int c = cb * 64 + cl;
    int g = c >> 3;
    float sum = 0.f, ssum = 0.f;
    for (int s = 0; s < 8; ++s) {
        sum  += stats[((b * 32 + g) * 8 + s) * 2];
        ssum += stats[((b * 32 + g) * 8 + s) * 2 + 1];
    }
    float mu = sum * (1.f / 32768.f);
    float var = ssum * (1.f / 32768.f) - mu * mu;
    float rsg = rsqrtf(var + 1e-5f);
    float ga = gamma[c], be = beta[c];
    __shared__ float T[64][66];
    const float4* p = reinterpret_cast<const float4*>(x + ((size_t)(b * CC + c)) * HW + nb * 64 + ch * 16);
    for (int j = 0; j < 4; ++j) {
        float4 v = p[j];
        int nbase = ch * 16 + j * 4;
        T[nbase + 0][cl] = (v.x - mu) * rsg * ga + be;
        T[nbase + 1][cl] = (v.y - mu) * rsg * ga + be;
        T[nbase + 2][cl] = (v.z - mu) * rsg * ga + be;
        T[nbase + 3][cl] = (v.w - mu) * rsg * ga + be;
    }
    __syncthreads();
    int nl = t >> 2;
    union { u16 u[16]; uint4 q[2]; } pk;
    for (int j = 0; j < 16; ++j) pk.u[j] = f2bf(T[nl][ch * 16 + j]);
    u16* dst = h_t + ((size_t)b * HW + nb * 64 + nl) * CC + cb * 64 + ch * 16;
    *reinterpret_cast<uint4*>(dst) = pk.q[0];
    *reinterpret_cast<uint4*>(dst + 8) = pk.q[1];
}

// ---------------- K3: QKV GEMM: [768x256] x [256x4096] per batch --------------------
__global__ __launch_bounds__(256) void k_qkv(const u16* __restrict__ wqkv, const u16* __restrict__ h_t,
                                             const float* __restrict__ qkv_b,
                                             u16* __restrict__ qk_t, u16* __restrict__ v_o) {
    int bid = blockIdx.x;          // 4 * 6 * 32 = 768
    int b = bid / 192;
    int rem = bid % 192;
    int om = rem >> 5;             // 0..5
    int nb = rem & 31;
    int o0 = om * 128, n0 = nb * 128;
    int t = threadIdx.x;
    int wid = t >> 6, lane = t & 63;
    int wm = wid >> 1, wn = wid & 1;
    int l15 = lane & 15, lg = lane >> 4;

    __shared__ u16 sA[128 * 40], sB[128 * 40];
    f32x4 acc[4][4];
    for (int i = 0; i < 4; ++i) for (int j = 0; j < 4; ++j) acc[i][j] = (f32x4)0.f;

    const u16* gA = wqkv + (size_t)o0 * 256;
    const u16* gB = h_t + ((size_t)b * HW + n0) * CC;
    int row = t >> 1, half = t & 1;

    for (int kt = 0; kt < 8; ++kt) {
        __syncthreads();
        {
            const uint4* pa = reinterpret_cast<const uint4*>(gA + (size_t)row * 256 + kt * 32 + half * 16);
            uint4 a0 = pa[0], a1 = pa[1];
            const uint4* pb = reinterpret_cast<const uint4*>(gB + (size_t)row * 256 + kt * 32 + half * 16);
            uint4 b0 = pb[0], b1 = pb[1];
            *reinterpret_cast<uint4*>(&sA[row * 40 + half * 16]) = a0;
            *reinterpret_cast<uint4*>(&sA[row * 40 + half * 16 + 8]) = a1;
            *reinterpret_cast<uint4*>(&sB[row * 40 + half * 16]) = b0;
            *reinterpret_cast<uint4*>(&sB[row * 40 + half * 16 + 8]) = b1;
        }
        __syncthreads();
        bf16x8 af[4], bfr[4];
        for (int mt = 0; mt < 4; ++mt)
            af[mt] = *reinterpret_cast<const bf16x8*>(&sA[(wm * 64 + mt * 16 + l15) * 40 + lg * 8]);
        for (int nt = 0; nt < 4; ++nt)
            bfr[nt] = *reinterpret_cast<const bf16x8*>(&sB[(wn * 64 + nt * 16 + l15) * 40 + lg * 8]);
        for (int mt = 0; mt < 4; ++mt)
            for (int nt = 0; nt < 4; ++nt)
                acc[mt][nt] = MFMA16(af[mt], bfr[nt], acc[mt][nt]);
    }

    // epilogue
    if (o0 < 512) {
        for (int mt = 0; mt < 4; ++mt) {
            int ob = o0 + wm * 64 + mt * 16 + lg * 4;
            float bias[4];
            for (int r = 0; r < 4; ++r) {
                int o = ob + r;
                bias[r] = qkv_b[o] * (o < 256 ? QSCALE : 1.0f);
            }
            for (int nt = 0; nt < 4; ++nt) {
                int n = n0 + wn * 64 + nt * 16 + l15;
                union { u16 u[4]; uint2 q; } pk;
                for (int r = 0; r < 4; ++r) pk.u[r] = f2bf(acc[mt][nt][r] + bias[r]);
                *reinterpret_cast<uint2*>(qk_t + ((size_t)b * HW + n) * 512 + ob) = pk.q;
            }
        }
    } else {
        for (int mt = 0; mt < 4; ++mt) {
            int ob = o0 + wm * 64 + mt * 16 + lg * 4;
            for (int nt = 0; nt < 4; ++nt) {
                int n = n0 + wn * 64 + nt * 16 + l15;
                for (int r = 0; r < 4; ++r) {
                    int o = ob + r;
                    float bias = qkv_b[o];
                    v_o[((size_t)b * 256 + (o - 512)) * HW + n] = f2bf(acc[mt][nt][r] + bias);
                }
            }
        }
    }
}

// ---------------- K4: flash attention, swapped 32x32, 8-wave key-split --------------
// Best measured structure (77.0-77.4 us). Grid 512 XCD-swizzled; K+V
// double-buffered LDS; prefetch issued AFTER the barrier (not drained by hipcc's
// pre-barrier vmcnt(0)); T5 setprio around MFMA clusters; fixed softmax max
// (m=0; logits ~N(0,0.1), fp32 sum safe to ~2^110) -> kg partials exactly
// additive: O = (O0+O1)/(l0+l1), combined via LDS at end.
// Register budget is EXACTLY saturated (64 VGPR + 64 AGPR accumulators at
// 4 waves/SIMD); any liveness extension spills (r4/r11 evidence).
__global__ __launch_bounds__(512, 4) void k_attn(const u16* __restrict__ qk_t, const u16* __restrict__ v_o,
                                                 u16* __restrict__ ao_t) {
    int bid = blockIdx.x;
    int swz = (bid & 7) * 64 + (bid >> 3);   // bijective; 64 consecutive tiles per XCD
    int qb = swz & 31, head = (swz >> 5) & 3, b = swz >> 7;
    int n0 = qb * 128;
    int t = threadIdx.x;
    int kg = t >> 8;                   // key group 0/1
    int wq = (t >> 6) & 3;             // q strip within group
    int lane = t & 63, l31 = lane & 31, h = lane >> 5;

    __shared__ u16 lds[2 * 2 * 2 * 64 * 72];   // 73728 B: [group][buf][K/V][64][72]

    // hoist Q fragments (B-operand layout: lane n=l31, c = h*8+j) — direct global
    const u16* qbase = qk_t + ((size_t)b * HW + n0 + wq * 32 + l31) * 512 + head * 64 + h * 8;
    bf16x8 qf[4];
#pragma unroll
    for (int cs = 0; cs < 4; ++cs) qf[cs] = *reinterpret_cast<const bf16x8*>(qbase + cs * 16);

    const u16* gK = qk_t + (size_t)b * HW * 512 + 256 + head * 64;
    const u16* gV = v_o + ((size_t)b * 256 + head * 64) * (size_t)HW;

    int tIn = t & 255;
    int srow = tIn >> 3, sch = tIn & 7;  // staging within group: 2 rows/thread/operand
    const u16* pk0 = gK + (size_t)(kg * 2048 + srow) * 512 + sch * 8;
    const u16* pk1 = pk0 + 32 * 512;
    const u16* pv0 = gV + (size_t)srow * HW + kg * 2048 + sch * 8;
    const u16* pv1 = pv0 + 32 * HW;
    uint4 rk0 = *reinterpret_cast<const uint4*>(pk0);
    uint4 rk1 = *reinterpret_cast<const uint4*>(pk1);
    uint4 rv0 = *reinterpret_cast<const uint4*>(pv0);
    uint4 rv1 = *reinterpret_cast<const uint4*>(pv1);

    f32x16 o0 = (f32x16)0.f, o1 = (f32x16)0.f;
    float l_run = 0.f;
    u16* gb = lds + kg * 18432;

    for (int ti = 0; ti < 32; ++ti) {
        u16* bK = gb + (ti & 1) * 9216;
        u16* bV = bK + 4608;
        *reinterpret_cast<uint4*>(bK + srow * 72 + sch * 8) = rk0;
        *reinterpret_cast<uint4*>(bK + (srow + 32) * 72 + sch * 8) = rk1;
        *reinterpret_cast<uint4*>(bV + srow * 72 + sch * 8) = rv0;
        *reinterpret_cast<uint4*>(bV + (srow + 32) * 72 + sch * 8) = rv1;
        __syncthreads();   // vmcnt already 0 here (writes consumed the loads)

        if (ti < 31) {     // prefetch issued AFTER the barrier: not drained, flies
            pk0 += 64 * 512; pk1 += 64 * 512; pv0 += 64; pv1 += 64;
            rk0 = *reinterpret_cast<const uint4*>(pk0);
            rk1 = *reinterpret_cast<const uint4*>(pk1);
            rv0 = *reinterpret_cast<const uint4*>(pv0);
            rv1 = *reinterpret_cast<const uint4*>(pv1);
        }

        // S^T[k][q] = K[k][c] * Q^T[c][q]
        f32x16 s0 = (f32x16)0.f, s1 = (f32x16)0.f;
        __builtin_amdgcn_s_setprio(1);
#pragma unroll
        for (int cs = 0; cs < 4; ++cs) {
            bf16x8 k0 = *reinterpret_cast<const bf16x8*>(bK + l31 * 72 + cs * 16 + h * 8);
            bf16x8 k1 = *reinterpret_cast<const bf16x8*>(bK + (l31 + 32) * 72 + cs * 16 + h * 8);
            s0 = MFMA32(k0, qf[cs], s0);
            s1 = MFMA32(k1, qf[cs], s1);
        }
        __builtin_amdgcn_s_setprio(0);

        // fixed-max softmax: P = exp2(S) directly; in-lane partial sum
        float ps = 0.f;
#pragma unroll
        for (int i = 0; i < 16; ++i) { float e = fast_exp2(s0[i]); s0[i] = e; ps += e; }
#pragma unroll
        for (int i = 0; i < 16; ++i) { float e = fast_exp2(s1[i]); s1[i] = e; ps += e; }
        l_run += ps;

        // pack P to bf16 dwords: dws[kt][2a+p] covers k = kt*32 + 8a + 4h + 2p + {0,1}
        unsigned dws[2][8];
#pragma unroll
        for (int a = 0; a < 4; ++a) {
            dws[0][2 * a]     = cvt_pk_bf16(s0[4 * a],     s0[4 * a + 1]);
            dws[0][2 * a + 1] = cvt_pk_bf16(s0[4 * a + 2], s0[4 * a + 3]);
            dws[1][2 * a]     = cvt_pk_bf16(s1[4 * a],     s1[4 * a + 1]);
            dws[1][2 * a + 1] = cvt_pk_bf16(s1[4 * a + 2], s1[4 * a + 3]);
        }
        // build PV B-fragments: frag[ks] needs k = 16ks + 8h + {0..7}
        bf16x8 pf[4];
#pragma unroll
        for (int ks = 0; ks < 4; ++ks) {
            int kt = ks >> 1, sf = ks & 1;
            unsigned A0 = dws[kt][4 * sf + 0], B0 = dws[kt][4 * sf + 2];
            unsigned A1 = dws[kt][4 * sf + 1], B1 = dws[kt][4 * sf + 3];
            plane_swap(A0, B0);
            plane_swap(A1, B1);
            union { unsigned d[4]; bf16x8 v; } u;
            u.d[0] = A0; u.d[1] = A1; u.d[2] = B0; u.d[3] = B1;
            pf[ks] = u.v;
        }

        // O^T[d][q] += V^T[d][k] * P^T[k][q]
        __builtin_amdgcn_s_setprio(1);
#pragma unroll
        for (int ks = 0; ks < 4; ++ks) {
            bf16x8 v0 = *reinterpret_cast<const bf16x8*>(bV + l31 * 72 + ks * 16 + h * 8);
            bf16x8 v1 = *reinterpret_cast<const bf16x8*>(bV + (l31 + 32) * 72 + ks * 16 + h * 8);
            o0 = MFMA32(v0, pf[ks], o0);
            o1 = MFMA32(v1, pf[ks], o1);
        }
        __builtin_amdgcn_s_setprio(0);
    }

    // full row-sum: add the other 32-key half within this group's tile columns
    l_run += __shfl_xor(l_run, 32);

    // -------- combine group partials (exactly additive under fixed max) --------
    float* Of = (float*)lds;                 // [wq][32 regs][64 lanes] = 32 KB
    float* Lf = (float*)lds + 8192;          // [wq*64+lane] = 1 KB
    u16* E = lds + 18432;                    // [128 q][72] u16 funnel (group-1 region)

    __syncthreads();                         // all compute done; LDS reusable
    if (kg == 1) {
#pragma unroll
        for (int i = 0; i < 16; ++i) {
            Of[wq * 2048 + i * 64 + lane] = o0[i];
            Of[wq * 2048 + (16 + i) * 64 + lane] = o1[i];
        }
        Lf[wq * 64 + lane] = l_run;
    }
    __syncthreads();
    if (kg == 0) {
#pragma unroll
        for (int i = 0; i < 16; ++i) {
            o0[i] += Of[wq * 2048 + i * 64 + lane];
            o1[i] += Of[wq * 2048 + (16 + i) * 64 + lane];
        }
        l_run += Lf[wq * 64 + lane];
        float inv = 1.0f / l_run;
        int qrow = wq * 32 + l31;
#pragma unroll
        for (int r = 0; r < 16; ++r) {
            int d = (r & 3) + 8 * (r >> 2) + 4 * h;
            E[qrow * 72 + d]      = f2bf(o0[r] * inv);
            E[qrow * 72 + 32 + d] = f2bf(o1[r] * inv);
        }
    }
    __syncthreads();
#pragma unroll
    for (int i = 0; i < 2; ++i) {
        int item = i * 512 + t;
        int row = item >> 3, cb = item & 7;
        uint4 w = *reinterpret_cast<const uint4*>(E + row * 72 + cb * 8);
        *reinterpret_cast<uint4*>(ao_t + ((size_t)b * HW + n0 + row) * 256 + head * 64 + cb * 8) = w;
    }
}

// ---------------- K5: proj GEMM + bias + residual -> out fp32 -----------------------
// BN=64 tiles -> grid 512 = 2 blocks/CU for latency hiding on the 136 MB epilogue.
__global__ __launch_bounds__(256) void k_proj(const u16* __restrict__ wproj, const u16* __restrict__ ao_t,
                                              const float* __restrict__ proj_b, const float* __restrict__ x,
                                              float* __restrict__ out) {
    int bid = blockIdx.x;          // 4 * 2 * 64 = 512
    int b = bid >> 7;
    int om = (bid >> 6) & 1;
    int nb = bid & 63;
    int o0 = om * 128, n0 = nb * 64;
    int t = threadIdx.x;
    int wid = t >> 6, lane = t & 63;
    int wm = wid >> 1, wn = wid & 1;
    int l15 = lane & 15, lg = lane >> 4;

    __shared__ u16 sA[128 * 40], sB[64 * 40];
    f32x4 acc[4][2];
    for (int i = 0; i < 4; ++i) for (int j = 0; j < 2; ++j) acc[i][j] = (f32x4)0.f;

    const u16* gA = wproj + (size_t)o0 * 256;
    const u16* gB = ao_t + ((size_t)b * HW + n0) * CC;
    int rowA = t >> 1, halfA = t & 1;
    int rowB = t >> 2, qB = t & 3;

    for (int kt = 0; kt < 8; ++kt) {
        __syncthreads();
        {
            const uint4* pa = reinterpret_cast<const uint4*>(gA + (size_t)rowA * 256 + kt * 32 + halfA * 16);
            uint4 a0 = pa[0], a1 = pa[1];
            uint4 b0 = *reinterpret_cast<const uint4*>(gB + (size_t)rowB * 256 + kt * 32 + qB * 8);
            *reinterpret_cast<uint4*>(&sA[rowA * 40 + halfA * 16]) = a0;
            *reinterpret_cast<uint4*>(&sA[rowA * 40 + halfA * 16 + 8]) = a1;
            *reinterpret_cast<uint4*>(&sB[rowB * 40 + qB * 8]) = b0;
        }
        __syncthreads();
        bf16x8 af[4], bfr[2];
        for (int mt = 0; mt < 4; ++mt)
            af[mt] = *reinterpret_cast<const bf16x8*>(&sA[(wm * 64 + mt * 16 + l15) * 40 + lg * 8]);
        for (int nt = 0; nt < 2; ++nt)
            bfr[nt] = *reinterpret_cast<const bf16x8*>(&sB[(wn * 32 + nt * 16 + l15) * 40 + lg * 8]);
        for (int mt = 0; mt < 4; ++mt)
            for (int nt = 0; nt < 2; ++nt)
                acc[mt][nt] = MFMA16(af[mt], bfr[nt], acc[mt][nt]);
    }

    for (int mt = 0; mt < 4; ++mt) {
        int ob = o0 + wm * 64 + mt * 16 + lg * 4;
        for (int nt = 0; nt < 2; ++nt) {
            int n = n0 + wn * 32 + nt * 16 + l15;
            for (int r = 0; r < 4; ++r) {
                int o = ob + r;
                size_t idx = ((size_t)(b * CC + o)) * HW + n;
                out[idx] = acc[mt][nt][r] + proj_b[o] + x[idx];
            }
        }
    }
}

// ---------------- launcher ----------------------------------------------------------
extern "C" void kernel_launch(void* const* d_in, const int* in_sizes, int n_in,
                              void* d_out, int out_size, void* d_ws, size_t ws_size,
                              hipStream_t stream) {
    const float* x      = (const float*)d_in[0];
    const float* gamma  = (const float*)d_in[1];
    const float* beta   = (const float*)d_in[2];
    const float* qkv_w  = (const float*)d_in[3];
    const float* qkv_b  = (const float*)d_in[4];
    const float* proj_w = (const float*)d_in[5];
    const float* proj_b = (const float*)d_in[6];
    float* out = (float*)d_out;
    char* ws = (char*)d_ws;

    float* stats = (float*)ws;                                   // 8 KB (1024 partials x2)
    u16* wqkv  = (u16*)(ws + 8192);                              // 384 KB
    u16* wproj = (u16*)(ws + 8192 + 393216);                     // 128 KB
    u16* h_t   = (u16*)(ws + 1048576);                           // 8 MB  [b][n][c]
    u16* qk_t  = (u16*)(ws + 1048576 + 8388608);                 // 16 MB [b][n][512]
    u16* v_o   = (u16*)(ws + 1048576 + 8388608 + 16777216);      // 8 MB  [b][256][n]
    u16* ao_t  = (u16*)(ws + 1048576 + 8388608 + 16777216 + 8388608); // 8 MB [b][n][c]

    k_wsc<<<dim3(2048), dim3(256), 0, stream>>>(qkv_w, proj_w, x, wqkv, wproj, stats);
    k_gnt<<<dim3(1024), dim3(256), 0, stream>>>(x, stats, gamma, beta, h_t);
    k_qkv<<<dim3(768), dim3(256), 0, stream>>>(wqkv, h_t, qkv_b, qk_t, v_o);
    k_attn<<<dim3(512), dim3(512), 0, stream>>>(qk_t, v_o, ao_t);
    k_proj<<<dim3(512), dim3(256), 0, stream>>>(wproj, ao_t, proj_b, x, out);
}